// Round 8
// baseline (1191.935 us; speedup 1.0000x reference)
//
#include <hip/hip_runtime.h>
#include <math.h>

#define N_NODES 50000
#define N_EDGES 800000
#define HID 64
#define HEADS 4
#define HC 256
#define NEG_SLOPE 0.2f
#define LN_EPS 1e-5f
#define GROUP 8   // edges per group in the fused kernel

__device__ __forceinline__ float bf2f(unsigned short u) {
    return __uint_as_float(((unsigned int)u) << 16);
}
__device__ __forceinline__ unsigned short f2bf(float f) {
    unsigned int u = __float_as_uint(f);
    u = (u + 0x7fffu + ((u >> 16) & 1u)) >> 16;   // RNE
    return (unsigned short)u;
}

// ---------------- K1: xl_bf = bf16(x@W_l+b_l), xr_bf = bf16(x@W_r+b_r) -----
__global__ __launch_bounds__(256) void k_node_transform(
    const float* __restrict__ x,
    const float* __restrict__ W_l, const float* __restrict__ b_l,
    const float* __restrict__ W_r, const float* __restrict__ b_r,
    unsigned short* __restrict__ xl_bf, unsigned short* __restrict__ xr_bf)
{
    __shared__ float xs[8][64];
    const int n0 = blockIdx.x * 8;
    const int t = threadIdx.x;
    for (int i = t; i < 8 * 64; i += 256) xs[i >> 6][i & 63] = x[n0 * 64 + i];
    __syncthreads();

    float accl[8], accr[8];
    const float bl = b_l[t], br = b_r[t];
#pragma unroll
    for (int n = 0; n < 8; n++) { accl[n] = bl; accr[n] = br; }
    for (int k = 0; k < 64; k++) {
        const float wl = W_l[k * 256 + t];
        const float wr = W_r[k * 256 + t];
#pragma unroll
        for (int n = 0; n < 8; n++) {
            accl[n] = fmaf(xs[n][k], wl, accl[n]);
            accr[n] = fmaf(xs[n][k], wr, accr[n]);
        }
    }
#pragma unroll
    for (int n = 0; n < 8; n++) {
        xl_bf[(n0 + n) * 256 + t] = f2bf(accl[n]);
        xr_bf[(n0 + n) * 256 + t] = f2bf(accr[n]);
    }
}

// ---------------- K2: histogram of dst ------------------------------------
__global__ __launch_bounds__(256) void k_hist(const int* __restrict__ ei, int* __restrict__ count)
{
    const int e = blockIdx.x * 256 + threadIdx.x;
    if (e < N_EDGES) atomicAdd(&count[ei[N_EDGES + e]], 1);
}

// ---------------- K3: exclusive scan (single block) ------------------------
__global__ __launch_bounds__(1024) void k_scan(const int* __restrict__ count, int* __restrict__ off)
{
    __shared__ int wsum[16];
    __shared__ int s_carry;
    const int t = threadIdx.x, lane = t & 63, wv = t >> 6;
    if (t == 0) s_carry = 0;
    __syncthreads();
    for (int base = 0; base < N_NODES; base += 8192) {
        const int idx0 = base + t * 8;
        int v[8];
#pragma unroll
        for (int j = 0; j < 8; j++) { int i = idx0 + j; v[j] = (i < N_NODES) ? count[i] : 0; }
#pragma unroll
        for (int j = 1; j < 8; j++) v[j] += v[j - 1];
        const int tot = v[7];
        int sc = tot;
#pragma unroll
        for (int s = 1; s < 64; s <<= 1) { int o = __shfl_up(sc, s, 64); if (lane >= s) sc += o; }
        if (lane == 63) wsum[wv] = sc;
        __syncthreads();
        const int carry = s_carry;
        int woff = 0;
        for (int u = 0; u < wv; u++) woff += wsum[u];
        const int ebase = carry + woff + (sc - tot);
#pragma unroll
        for (int j = 0; j < 8; j++) {
            int i = idx0 + j;
            if (i < N_NODES) off[i] = ebase + (j ? v[j - 1] : 0);
        }
        __syncthreads();
        if (t == 0) { int tt = 0; for (int u = 0; u < 16; u++) tt += wsum[u]; s_carry = carry + tt; }
        __syncthreads();
    }
    if (threadIdx.x == 0) off[N_NODES] = s_carry;
}

// ---------------- K4: scatter src/eid into CSR slots -----------------------
__global__ __launch_bounds__(256) void k_scatter(
    const int* __restrict__ ei, const int* __restrict__ off, int* __restrict__ cursor,
    int* __restrict__ csr_src, int* __restrict__ eid_csr)
{
    const int e = blockIdx.x * 256 + threadIdx.x;
    if (e < N_EDGES) {
        const int s = ei[e];
        const int d = ei[N_EDGES + e];
        const int pos = off[d] + atomicAdd(&cursor[d], 1);
        csr_src[pos] = s;
        eid_csr[pos] = e;
    }
}

// ---------------- K5: FUSED alpha + aggregate + MLP + LN + out-GEMM --------
// 4 waves/block, wave = one node, lane owns channels [lane*4, lane*4+4).
// Per 8-edge group: edge_attr staged into per-wave LDS via coalesced vector
// loads; xl rows loaded once, used for logit AND aggregation.
// #pragma unroll 2 on the W_e loop keeps VGPR ~100 (full unroll -> 136+,
// occupancy 11%); __launch_bounds__(256,4) caps at 128 as insurance.
__global__ __launch_bounds__(256, 4) void k_fused(
    const int* __restrict__ off, const int* __restrict__ csr_src,
    const int* __restrict__ eid_csr, const float* __restrict__ edge_attr,
    const float* __restrict__ W_e, const float* __restrict__ att,
    const unsigned short* __restrict__ xl_bf, const unsigned short* __restrict__ xr_bf,
    const float* __restrict__ x, const float* __restrict__ bias_gat,
    const float* __restrict__ W1, const float* __restrict__ b1,
    const float* __restrict__ gamma, const float* __restrict__ beta,
    const float* __restrict__ W2, const float* __restrict__ b2,
    float* __restrict__ out)
{
    __shared__ float xs[4][64];
    __shared__ float zs[4][256];
    __shared__ float ea_s[4][GROUP][32];   // per-wave edge_attr staging
    __shared__ float redS[4][4], redQ[4][4];
    __shared__ float part[4][4][64];

    const int n0 = blockIdx.x * 4;
    const int t = threadIdx.x;
    const int lane = t & 63, wv = t >> 6;
    const int node = n0 + wv;

    for (int i = t; i < 4 * 64; i += 256) xs[i >> 6][i & 63] = x[n0 * 64 + i];

    const float4 att4 = ((const float4*)att)[lane];
    const ushort4 xru = ((const ushort4*)(xr_bf + (size_t)node * 256))[lane];
    const float xr0 = bf2f(xru.x), xr1 = bf2f(xru.y), xr2 = bf2f(xru.z), xr3 = bf2f(xru.w);

    const int mylo = off[node], myhi = off[node + 1];
    float4 g = make_float4(0.f, 0.f, 0.f, 0.f);
    float dsum = 0.f;

    for (int p0 = mylo; p0 < myhi; p0 += GROUP) {
        // eids for this group live in lanes 0..GROUP-1
        int eidv = 0;
        {
            int p = p0 + lane; if (p > myhi - 1) p = myhi - 1;
            if (lane < GROUP) eidv = eid_csr[p];
        }
        // stage GROUP x 32 floats of edge_attr into per-wave LDS (coalesced)
#pragma unroll
        for (int i = 0; i < (GROUP * 32) / 64; i++) {
            const int idx = i * 64 + lane;
            const int jj = idx >> 5, kk = idx & 31;
            const int e = __shfl(eidv, jj, 64);
            ea_s[wv][jj][kk] = edge_attr[(size_t)e * 32 + kk];
        }
        // xl row gathers (independent, 8 in flight)
        ushort4 row[GROUP];
#pragma unroll
        for (int j = 0; j < GROUP; j++) {
            int p = p0 + j; if (p > myhi - 1) p = myhi - 1;   // clamp pads
            const int src = csr_src[p];
            row[j] = ((const ushort4*)(xl_bf + (size_t)src * 256))[lane];
        }
        float4 acc[GROUP];
#pragma unroll
        for (int j = 0; j < GROUP; j++) {
            acc[j].x = bf2f(row[j].x) + xr0;
            acc[j].y = bf2f(row[j].y) + xr1;
            acc[j].z = bf2f(row[j].z) + xr2;
            acc[j].w = bf2f(row[j].w) + xr3;
        }
        // W_e transform: k outer (W_e row reused across 8 edges), LDS broadcast ea.
        // unroll 2 (NOT full): full unroll hoists 32 float4 loads -> VGPR blowup.
#pragma unroll 2
        for (int k = 0; k < 32; k++) {
            const float4 we = ((const float4*)(W_e + k * 256))[lane];
#pragma unroll
            for (int j = 0; j < GROUP; j++) {
                const float e = ea_s[wv][j][k];
                acc[j].x = fmaf(e, we.x, acc[j].x);
                acc[j].y = fmaf(e, we.y, acc[j].y);
                acc[j].z = fmaf(e, we.z, acc[j].z);
                acc[j].w = fmaf(e, we.w, acc[j].w);
            }
        }
#pragma unroll
        for (int j = 0; j < GROUP; j++) {
            float4 m = acc[j];
            m.x = (m.x > 0.f) ? m.x : NEG_SLOPE * m.x;
            m.y = (m.y > 0.f) ? m.y : NEG_SLOPE * m.y;
            m.z = (m.z > 0.f) ? m.z : NEG_SLOPE * m.z;
            m.w = (m.w > 0.f) ? m.w : NEG_SLOPE * m.w;
            float s = m.x * att4.x + m.y * att4.y + m.z * att4.z + m.w * att4.w;
            s += __shfl_xor(s, 1, 64);
            s += __shfl_xor(s, 2, 64);
            s += __shfl_xor(s, 4, 64);
            s += __shfl_xor(s, 8, 64);   // 16-lane group = one head
            float wexp = __expf(fminf(s, 60.f));
            if (p0 + j >= myhi) wexp = 0.f;   // mask pad slots
            dsum += wexp;
            g.x = fmaf(wexp, bf2f(row[j].x), g.x);
            g.y = fmaf(wexp, bf2f(row[j].y), g.y);
            g.z = fmaf(wexp, bf2f(row[j].z), g.z);
            g.w = fmaf(wexp, bf2f(row[j].w), g.w);
        }
    }
    const float inv = 1.f / (dsum + 1e-16f);
    g.x *= inv; g.y *= inv; g.z *= inv; g.w *= inv;
    ((float4*)zs[wv])[lane] = g;
    __syncthreads();

    // xl1 = tanh(x@W1+b1), channel t, 4 nodes
    float a1[4];
    const float b1v = b1[t];
#pragma unroll
    for (int n = 0; n < 4; n++) a1[n] = b1v;
    for (int k = 0; k < 64; k++) {
        const float w1v = W1[k * 256 + t];
#pragma unroll
        for (int n = 0; n < 4; n++) a1[n] = fmaf(xs[n][k], w1v, a1[n]);
    }

    const float bg = bias_gat[t];
    float z[4];
#pragma unroll
    for (int n = 0; n < 4; n++) z[n] = tanhf(a1[n]) + zs[n][t] + bg;

    // LayerNorm over 256 channels per node
    const float gm = gamma[t], bt = beta[t];
#pragma unroll
    for (int n = 0; n < 4; n++) {
        float s = z[n], q = z[n] * z[n];
#pragma unroll
        for (int m = 1; m < 64; m <<= 1) { s += __shfl_xor(s, m, 64); q += __shfl_xor(q, m, 64); }
        if (lane == 0) { redS[n][wv] = s; redQ[n][wv] = q; }
    }
    __syncthreads();
#pragma unroll
    for (int n = 0; n < 4; n++) {
        const float s = redS[n][0] + redS[n][1] + redS[n][2] + redS[n][3];
        const float q = redQ[n][0] + redQ[n][1] + redQ[n][2] + redQ[n][3];
        const float mu = s * (1.f / 256.f);
        const float var = q * (1.f / 256.f) - mu * mu;
        const float ivn = rsqrtf(var + LN_EPS);
        zs[n][t] = (z[n] - mu) * ivn * gm + bt;
    }
    __syncthreads();

    // out = tanh(z@W2 + b2): thread t -> output col j=t&63, K-chunk q=t>>6
    const int j = t & 63, q = t >> 6;
    float p[4] = {0.f, 0.f, 0.f, 0.f};
    for (int c0 = 0; c0 < 64; c0++) {
        const int c = q * 64 + c0;
        const float w2v = W2[c * 64 + j];
#pragma unroll
        for (int n = 0; n < 4; n++) p[n] = fmaf(zs[n][c], w2v, p[n]);
    }
#pragma unroll
    for (int n = 0; n < 4; n++) part[n][q][j] = p[n];
    __syncthreads();
    {
        const int n = t >> 6, jj = t & 63;
        const float s = part[n][0][jj] + part[n][1][jj] + part[n][2][jj] + part[n][3][jj];
        out[(n0 + n) * 64 + jj] = tanhf(s + b2[jj]);
    }
}

// ---------------- launcher --------------------------------------------------
extern "C" void kernel_launch(void* const* d_in, const int* in_sizes, int n_in,
                              void* d_out, int out_size, void* d_ws, size_t ws_size,
                              hipStream_t stream)
{
    const float* x         = (const float*)d_in[0];
    const int*   ei        = (const int*)d_in[1];
    const float* edge_attr = (const float*)d_in[2];
    const float* W_l       = (const float*)d_in[3];
    const float* b_l       = (const float*)d_in[4];
    const float* W_r       = (const float*)d_in[5];
    const float* b_r       = (const float*)d_in[6];
    const float* W_e       = (const float*)d_in[7];
    const float* att       = (const float*)d_in[8];
    const float* bias_gat  = (const float*)d_in[9];
    const float* W1        = (const float*)d_in[10];
    const float* b1        = (const float*)d_in[11];
    const float* gamma     = (const float*)d_in[12];
    const float* beta      = (const float*)d_in[13];
    const float* W2        = (const float*)d_in[14];
    const float* b2        = (const float*)d_in[15];
    float* out = (float*)d_out;

    char* ws = (char*)d_ws;
    unsigned short* xl_bf = (unsigned short*)ws;  ws += (size_t)N_NODES * HC * 2;  // 25.6 MB
    unsigned short* xr_bf = (unsigned short*)ws;  ws += (size_t)N_NODES * HC * 2;  // 25.6 MB
    int* csr_src          = (int*)ws;             ws += (size_t)N_EDGES * 4;
    int* eid_csr          = (int*)ws;             ws += (size_t)N_EDGES * 4;
    int* count            = (int*)ws;             ws += (size_t)N_NODES * 4;
    int* cursor           = (int*)ws;             ws += (size_t)N_NODES * 4;
    int* off              = (int*)ws;             ws += (size_t)(N_NODES + 1) * 4;

    // zero count + cursor (contiguous)
    hipMemsetAsync(count, 0, 2 * (size_t)N_NODES * sizeof(int), stream);

    k_node_transform<<<N_NODES / 8, 256, 0, stream>>>(x, W_l, b_l, W_r, b_r, xl_bf, xr_bf);
    k_hist<<<(N_EDGES + 255) / 256, 256, 0, stream>>>(ei, count);
    k_scan<<<1, 1024, 0, stream>>>(count, off);
    k_scatter<<<(N_EDGES + 255) / 256, 256, 0, stream>>>(ei, off, cursor, csr_src, eid_csr);
    k_fused<<<N_NODES / 4, 256, 0, stream>>>(off, csr_src, eid_csr, edge_attr, W_e, att,
                                             xl_bf, xr_bf, x, bias_gat,
                                             W1, b1, gamma, beta, W2, b2, out);
}

// Round 9
// 973.054 us; speedup vs baseline: 1.2249x; 1.2249x over previous
//
#include <hip/hip_runtime.h>
#include <math.h>

#define N_NODES 50000
#define N_EDGES 800000
#define HID 64
#define HEADS 4
#define HC 256
#define NEG_SLOPE 0.2f
#define LN_EPS 1e-5f
#define GROUP 8   // edges per group in the fused kernel

__device__ __forceinline__ float bf2f(unsigned short u) {
    return __uint_as_float(((unsigned int)u) << 16);
}
__device__ __forceinline__ unsigned short f2bf(float f) {
    unsigned int u = __float_as_uint(f);
    u = (u + 0x7fffu + ((u >> 16) & 1u)) >> 16;   // RNE
    return (unsigned short)u;
}

// ---------------- K1: xl_bf = bf16(x@W_l+b_l), xr_bf = bf16(x@W_r+b_r) -----
__global__ __launch_bounds__(256) void k_node_transform(
    const float* __restrict__ x,
    const float* __restrict__ W_l, const float* __restrict__ b_l,
    const float* __restrict__ W_r, const float* __restrict__ b_r,
    unsigned short* __restrict__ xl_bf, unsigned short* __restrict__ xr_bf)
{
    __shared__ float xs[8][64];
    const int n0 = blockIdx.x * 8;
    const int t = threadIdx.x;
    for (int i = t; i < 8 * 64; i += 256) xs[i >> 6][i & 63] = x[n0 * 64 + i];
    __syncthreads();

    float accl[8], accr[8];
    const float bl = b_l[t], br = b_r[t];
#pragma unroll
    for (int n = 0; n < 8; n++) { accl[n] = bl; accr[n] = br; }
    for (int k = 0; k < 64; k++) {
        const float wl = W_l[k * 256 + t];
        const float wr = W_r[k * 256 + t];
#pragma unroll
        for (int n = 0; n < 8; n++) {
            accl[n] = fmaf(xs[n][k], wl, accl[n]);
            accr[n] = fmaf(xs[n][k], wr, accr[n]);
        }
    }
#pragma unroll
    for (int n = 0; n < 8; n++) {
        xl_bf[(n0 + n) * 256 + t] = f2bf(accl[n]);
        xr_bf[(n0 + n) * 256 + t] = f2bf(accr[n]);
    }
}

// ---------------- K2: histogram of dst ------------------------------------
__global__ __launch_bounds__(256) void k_hist(const int* __restrict__ ei, int* __restrict__ count)
{
    const int e = blockIdx.x * 256 + threadIdx.x;
    if (e < N_EDGES) atomicAdd(&count[ei[N_EDGES + e]], 1);
}

// ---------------- K3: exclusive scan (single block) ------------------------
__global__ __launch_bounds__(1024) void k_scan(const int* __restrict__ count, int* __restrict__ off)
{
    __shared__ int wsum[16];
    __shared__ int s_carry;
    const int t = threadIdx.x, lane = t & 63, wv = t >> 6;
    if (t == 0) s_carry = 0;
    __syncthreads();
    for (int base = 0; base < N_NODES; base += 8192) {
        const int idx0 = base + t * 8;
        int v[8];
#pragma unroll
        for (int j = 0; j < 8; j++) { int i = idx0 + j; v[j] = (i < N_NODES) ? count[i] : 0; }
#pragma unroll
        for (int j = 1; j < 8; j++) v[j] += v[j - 1];
        const int tot = v[7];
        int sc = tot;
#pragma unroll
        for (int s = 1; s < 64; s <<= 1) { int o = __shfl_up(sc, s, 64); if (lane >= s) sc += o; }
        if (lane == 63) wsum[wv] = sc;
        __syncthreads();
        const int carry = s_carry;
        int woff = 0;
        for (int u = 0; u < wv; u++) woff += wsum[u];
        const int ebase = carry + woff + (sc - tot);
#pragma unroll
        for (int j = 0; j < 8; j++) {
            int i = idx0 + j;
            if (i < N_NODES) off[i] = ebase + (j ? v[j - 1] : 0);
        }
        __syncthreads();
        if (t == 0) { int tt = 0; for (int u = 0; u < 16; u++) tt += wsum[u]; s_carry = carry + tt; }
        __syncthreads();
    }
    if (threadIdx.x == 0) off[N_NODES] = s_carry;
}

// ---------------- K4: scatter src + PERMUTED bf16 edge_attr into CSR -------
// Read of edge_attr is thread=edge -> fully coalesced; write is 64B scatter.
// Removes the eid indirection from the hot kernel entirely.
__global__ __launch_bounds__(256) void k_scatter(
    const int* __restrict__ ei, const int* __restrict__ off, int* __restrict__ cursor,
    const float* __restrict__ edge_attr,
    int* __restrict__ csr_src, unsigned short* __restrict__ ea_csr)
{
    const int e = blockIdx.x * 256 + threadIdx.x;
    if (e < N_EDGES) {
        const int s = ei[e];
        const int d = ei[N_EDGES + e];
        const int pos = off[d] + atomicAdd(&cursor[d], 1);
        csr_src[pos] = s;
        const float4* src4 = (const float4*)(edge_attr + (size_t)e * 32);
        ushort4* dst4 = (ushort4*)(ea_csr + (size_t)pos * 32);
#pragma unroll
        for (int i = 0; i < 8; i++) {
            const float4 v = src4[i];
            ushort4 u;
            u.x = f2bf(v.x); u.y = f2bf(v.y); u.z = f2bf(v.z); u.w = f2bf(v.w);
            dst4[i] = u;
        }
    }
}

// ---------------- K5: FUSED pipelined alpha+aggregate + MLP+LN+GEMM --------
// 4 waves/block, wave = one node, lane owns channels [lane*4, lane*4+4).
// Software pipeline per 8-edge group:
//   (a) issue row gathers          (consumed at (e), ~2048 cyc later)
//   (b) issue NEXT group ea load   (consumed at (d))
//   (c) W_e FMA loop on ea staged LAST iteration (double-buffered LDS)
//   (d) ds_write next ea buffer
//   (e) deferred row-add, leaky, logit, exp, aggregate
__global__ __launch_bounds__(256) void k_fused(
    const int* __restrict__ off, const int* __restrict__ csr_src,
    const unsigned short* __restrict__ ea_csr,
    const float* __restrict__ W_e, const float* __restrict__ att,
    const unsigned short* __restrict__ xl_bf, const unsigned short* __restrict__ xr_bf,
    const float* __restrict__ x, const float* __restrict__ bias_gat,
    const float* __restrict__ W1, const float* __restrict__ b1,
    const float* __restrict__ gamma, const float* __restrict__ beta,
    const float* __restrict__ W2, const float* __restrict__ b2,
    float* __restrict__ out)
{
    __shared__ float xs[4][64];
    __shared__ float zs[4][256];
    __shared__ float ea_s[4][2][GROUP][32];   // per-wave double-buffered ea
    __shared__ float redS[4][4], redQ[4][4];
    __shared__ float part[4][4][64];

    const int n0 = blockIdx.x * 4;
    const int t = threadIdx.x;
    const int lane = t & 63, wv = t >> 6;
    const int node = n0 + wv;

    for (int i = t; i < 4 * 64; i += 256) xs[i >> 6][i & 63] = x[n0 * 64 + i];

    const float4 att4 = ((const float4*)att)[lane];
    const ushort4 xru = ((const ushort4*)(xr_bf + (size_t)node * 256))[lane];
    const float xr0 = bf2f(xru.x), xr1 = bf2f(xru.y), xr2 = bf2f(xru.z), xr3 = bf2f(xru.w);

    const int mylo = off[node], myhi = off[node + 1];
    float4 g = make_float4(0.f, 0.f, 0.f, 0.f);
    float dsum = 0.f;

    const int jrow = lane >> 3;        // staging: edge slot this lane fills
    const int kcol = (lane & 7) * 4;   // staging: channel quad

    if (mylo < myhi) {
        const int eamax = myhi * 32 - 4;
        // prologue: stage group 0 into buf 0
        {
            const int idx = min(mylo * 32 + lane * 4, eamax);
            const ushort4 u = *(const ushort4*)(ea_csr + idx);
            *(float4*)&ea_s[wv][0][jrow][kcol] =
                make_float4(bf2f(u.x), bf2f(u.y), bf2f(u.z), bf2f(u.w));
        }
        int buf = 0;
        for (int p0 = mylo; p0 < myhi; p0 += GROUP) {
            // (a) row gathers for this group
            ushort4 row[GROUP];
#pragma unroll
            for (int j = 0; j < GROUP; j++) {
                const int p = min(p0 + j, myhi - 1);
                const int src = csr_src[p];
                row[j] = ((const ushort4*)(xl_bf + (size_t)src * 256))[lane];
            }
            // (b) next group's ea load (contiguous, index-free)
            const int idxn = min((p0 + GROUP) * 32 + lane * 4, eamax);
            const ushort4 un = *(const ushort4*)(ea_csr + idxn);
            // (c) W_e transform from LDS staged last iteration
            float4 acc[GROUP];
#pragma unroll
            for (int j = 0; j < GROUP; j++) acc[j] = make_float4(0.f, 0.f, 0.f, 0.f);
#pragma unroll 8
            for (int k = 0; k < 32; k++) {
                const float4 we = ((const float4*)(W_e + k * 256))[lane];
#pragma unroll
                for (int j = 0; j < GROUP; j++) {
                    const float e = ea_s[wv][buf][j][k];
                    acc[j].x = fmaf(e, we.x, acc[j].x);
                    acc[j].y = fmaf(e, we.y, acc[j].y);
                    acc[j].z = fmaf(e, we.z, acc[j].z);
                    acc[j].w = fmaf(e, we.w, acc[j].w);
                }
            }
            // (d) stage next buffer
            *(float4*)&ea_s[wv][buf ^ 1][jrow][kcol] =
                make_float4(bf2f(un.x), bf2f(un.y), bf2f(un.z), bf2f(un.w));
            // (e) deferred row-add, leaky, logit, exp, aggregate
#pragma unroll
            for (int j = 0; j < GROUP; j++) {
                float4 rf;
                rf.x = bf2f(row[j].x); rf.y = bf2f(row[j].y);
                rf.z = bf2f(row[j].z); rf.w = bf2f(row[j].w);
                float4 m;
                m.x = acc[j].x + rf.x + xr0;
                m.y = acc[j].y + rf.y + xr1;
                m.z = acc[j].z + rf.z + xr2;
                m.w = acc[j].w + rf.w + xr3;
                m.x = (m.x > 0.f) ? m.x : NEG_SLOPE * m.x;
                m.y = (m.y > 0.f) ? m.y : NEG_SLOPE * m.y;
                m.z = (m.z > 0.f) ? m.z : NEG_SLOPE * m.z;
                m.w = (m.w > 0.f) ? m.w : NEG_SLOPE * m.w;
                float s = m.x * att4.x + m.y * att4.y + m.z * att4.z + m.w * att4.w;
                s += __shfl_xor(s, 1, 64);
                s += __shfl_xor(s, 2, 64);
                s += __shfl_xor(s, 4, 64);
                s += __shfl_xor(s, 8, 64);   // 16-lane group = one head
                float wexp = __expf(fminf(s, 60.f));
                if (p0 + j >= myhi) wexp = 0.f;   // mask pad slots
                dsum += wexp;
                g.x = fmaf(wexp, rf.x, g.x);
                g.y = fmaf(wexp, rf.y, g.y);
                g.z = fmaf(wexp, rf.z, g.z);
                g.w = fmaf(wexp, rf.w, g.w);
            }
            buf ^= 1;
        }
    }
    const float inv = 1.f / (dsum + 1e-16f);
    g.x *= inv; g.y *= inv; g.z *= inv; g.w *= inv;
    ((float4*)zs[wv])[lane] = g;
    __syncthreads();

    // xl1 = tanh(x@W1+b1), channel t, 4 nodes
    float a1[4];
    const float b1v = b1[t];
#pragma unroll
    for (int n = 0; n < 4; n++) a1[n] = b1v;
    for (int k = 0; k < 64; k++) {
        const float w1v = W1[k * 256 + t];
#pragma unroll
        for (int n = 0; n < 4; n++) a1[n] = fmaf(xs[n][k], w1v, a1[n]);
    }

    const float bg = bias_gat[t];
    float z[4];
#pragma unroll
    for (int n = 0; n < 4; n++) z[n] = tanhf(a1[n]) + zs[n][t] + bg;

    // LayerNorm over 256 channels per node
    const float gm = gamma[t], bt = beta[t];
#pragma unroll
    for (int n = 0; n < 4; n++) {
        float s = z[n], q = z[n] * z[n];
#pragma unroll
        for (int m = 1; m < 64; m <<= 1) { s += __shfl_xor(s, m, 64); q += __shfl_xor(q, m, 64); }
        if (lane == 0) { redS[n][wv] = s; redQ[n][wv] = q; }
    }
    __syncthreads();
#pragma unroll
    for (int n = 0; n < 4; n++) {
        const float s = redS[n][0] + redS[n][1] + redS[n][2] + redS[n][3];
        const float q = redQ[n][0] + redQ[n][1] + redQ[n][2] + redQ[n][3];
        const float mu = s * (1.f / 256.f);
        const float var = q * (1.f / 256.f) - mu * mu;
        const float ivn = rsqrtf(var + LN_EPS);
        zs[n][t] = (z[n] - mu) * ivn * gm + bt;
    }
    __syncthreads();

    // out = tanh(z@W2 + b2): thread t -> output col j=t&63, K-chunk q=t>>6
    const int j = t & 63, q = t >> 6;
    float p[4] = {0.f, 0.f, 0.f, 0.f};
    for (int c0 = 0; c0 < 64; c0++) {
        const int c = q * 64 + c0;
        const float w2v = W2[c * 64 + j];
#pragma unroll
        for (int n = 0; n < 4; n++) p[n] = fmaf(zs[n][c], w2v, p[n]);
    }
#pragma unroll
    for (int n = 0; n < 4; n++) part[n][q][j] = p[n];
    __syncthreads();
    {
        const int n = t >> 6, jj = t & 63;
        const float s = part[n][0][jj] + part[n][1][jj] + part[n][2][jj] + part[n][3][jj];
        out[(n0 + n) * 64 + jj] = tanhf(s + b2[jj]);
    }
}

// ---------------- launcher --------------------------------------------------
extern "C" void kernel_launch(void* const* d_in, const int* in_sizes, int n_in,
                              void* d_out, int out_size, void* d_ws, size_t ws_size,
                              hipStream_t stream)
{
    const float* x         = (const float*)d_in[0];
    const int*   ei        = (const int*)d_in[1];
    const float* edge_attr = (const float*)d_in[2];
    const float* W_l       = (const float*)d_in[3];
    const float* b_l       = (const float*)d_in[4];
    const float* W_r       = (const float*)d_in[5];
    const float* b_r       = (const float*)d_in[6];
    const float* W_e       = (const float*)d_in[7];
    const float* att       = (const float*)d_in[8];
    const float* bias_gat  = (const float*)d_in[9];
    const float* W1        = (const float*)d_in[10];
    const float* b1        = (const float*)d_in[11];
    const float* gamma     = (const float*)d_in[12];
    const float* beta      = (const float*)d_in[13];
    const float* W2        = (const float*)d_in[14];
    const float* b2        = (const float*)d_in[15];
    float* out = (float*)d_out;

    char* ws = (char*)d_ws;
    unsigned short* xl_bf  = (unsigned short*)ws;  ws += (size_t)N_NODES * HC * 2;   // 25.6 MB
    unsigned short* xr_bf  = (unsigned short*)ws;  ws += (size_t)N_NODES * HC * 2;   // 25.6 MB
    unsigned short* ea_csr = (unsigned short*)ws;  ws += (size_t)N_EDGES * 32 * 2;   // 51.2 MB
    int* csr_src           = (int*)ws;             ws += (size_t)N_EDGES * 4;
    int* count             = (int*)ws;             ws += (size_t)N_NODES * 4;
    int* cursor            = (int*)ws;             ws += (size_t)N_NODES * 4;
    int* off               = (int*)ws;             ws += (size_t)(N_NODES + 1) * 4;

    // zero count + cursor (contiguous)
    hipMemsetAsync(count, 0, 2 * (size_t)N_NODES * sizeof(int), stream);

    k_node_transform<<<N_NODES / 8, 256, 0, stream>>>(x, W_l, b_l, W_r, b_r, xl_bf, xr_bf);
    k_hist<<<(N_EDGES + 255) / 256, 256, 0, stream>>>(ei, count);
    k_scan<<<1, 1024, 0, stream>>>(count, off);
    k_scatter<<<(N_EDGES + 255) / 256, 256, 0, stream>>>(ei, off, cursor, edge_attr,
                                                         csr_src, ea_csr);
    k_fused<<<N_NODES / 4, 256, 0, stream>>>(off, csr_src, ea_csr, W_e, att,
                                             xl_bf, xr_bf, x, bias_gat,
                                             W1, b1, gamma, beta, W2, b2, out);
}

// Round 10
// 945.954 us; speedup vs baseline: 1.2600x; 1.0286x over previous
//
#include <hip/hip_runtime.h>
#include <math.h>

#define N_NODES 50000
#define N_EDGES 800000
#define HID 64
#define HEADS 4
#define HC 256
#define NEG_SLOPE 0.2f
#define LN_EPS 1e-5f

typedef __attribute__((ext_vector_type(8))) short bf16x8;
typedef __attribute__((ext_vector_type(4))) float f32x4;

__device__ __forceinline__ float bf2f(unsigned short u) {
    return __uint_as_float(((unsigned int)u) << 16);
}
__device__ __forceinline__ unsigned short f2bf(float f) {
    unsigned int u = __float_as_uint(f);
    u = (u + 0x7fffu + ((u >> 16) & 1u)) >> 16;   // RNE
    return (unsigned short)u;
}

// ---------------- K1: xl_bf = bf16(x@W_l+b_l), xr_bf = bf16(x@W_r+b_r) -----
__global__ __launch_bounds__(256) void k_node_transform(
    const float* __restrict__ x,
    const float* __restrict__ W_l, const float* __restrict__ b_l,
    const float* __restrict__ W_r, const float* __restrict__ b_r,
    unsigned short* __restrict__ xl_bf, unsigned short* __restrict__ xr_bf)
{
    __shared__ float xs[8][64];
    const int n0 = blockIdx.x * 8;
    const int t = threadIdx.x;
    for (int i = t; i < 8 * 64; i += 256) xs[i >> 6][i & 63] = x[n0 * 64 + i];
    __syncthreads();

    float accl[8], accr[8];
    const float bl = b_l[t], br = b_r[t];
#pragma unroll
    for (int n = 0; n < 8; n++) { accl[n] = bl; accr[n] = br; }
    for (int k = 0; k < 64; k++) {
        const float wl = W_l[k * 256 + t];
        const float wr = W_r[k * 256 + t];
#pragma unroll
        for (int n = 0; n < 8; n++) {
            accl[n] = fmaf(xs[n][k], wl, accl[n]);
            accr[n] = fmaf(xs[n][k], wr, accr[n]);
        }
    }
#pragma unroll
    for (int n = 0; n < 8; n++) {
        xl_bf[(n0 + n) * 256 + t] = f2bf(accl[n]);
        xr_bf[(n0 + n) * 256 + t] = f2bf(accr[n]);
    }
}

// ---------------- K2: histogram of dst ------------------------------------
__global__ __launch_bounds__(256) void k_hist(const int* __restrict__ ei, int* __restrict__ count)
{
    const int e = blockIdx.x * 256 + threadIdx.x;
    if (e < N_EDGES) atomicAdd(&count[ei[N_EDGES + e]], 1);
}

// ---------------- K3: exclusive scan (single block) ------------------------
__global__ __launch_bounds__(1024) void k_scan(const int* __restrict__ count, int* __restrict__ off)
{
    __shared__ int wsum[16];
    __shared__ int s_carry;
    const int t = threadIdx.x, lane = t & 63, wv = t >> 6;
    if (t == 0) s_carry = 0;
    __syncthreads();
    for (int base = 0; base < N_NODES; base += 8192) {
        const int idx0 = base + t * 8;
        int v[8];
#pragma unroll
        for (int j = 0; j < 8; j++) { int i = idx0 + j; v[j] = (i < N_NODES) ? count[i] : 0; }
#pragma unroll
        for (int j = 1; j < 8; j++) v[j] += v[j - 1];
        const int tot = v[7];
        int sc = tot;
#pragma unroll
        for (int s = 1; s < 64; s <<= 1) { int o = __shfl_up(sc, s, 64); if (lane >= s) sc += o; }
        if (lane == 63) wsum[wv] = sc;
        __syncthreads();
        const int carry = s_carry;
        int woff = 0;
        for (int u = 0; u < wv; u++) woff += wsum[u];
        const int ebase = carry + woff + (sc - tot);
#pragma unroll
        for (int j = 0; j < 8; j++) {
            int i = idx0 + j;
            if (i < N_NODES) off[i] = ebase + (j ? v[j - 1] : 0);
        }
        __syncthreads();
        if (t == 0) { int tt = 0; for (int u = 0; u < 16; u++) tt += wsum[u]; s_carry = carry + tt; }
        __syncthreads();
    }
    if (threadIdx.x == 0) off[N_NODES] = s_carry;
}

// ---------------- K4: scatter src + PERMUTED bf16 edge_attr into CSR -------
// ea_csr rows (32 bf16 = 64B) are exactly the MFMA A-operand source layout.
__global__ __launch_bounds__(256) void k_scatter(
    const int* __restrict__ ei, const int* __restrict__ off, int* __restrict__ cursor,
    const float* __restrict__ edge_attr,
    int* __restrict__ csr_src, unsigned short* __restrict__ ea_csr)
{
    const int e = blockIdx.x * 256 + threadIdx.x;
    if (e < N_EDGES) {
        const int s = ei[e];
        const int d = ei[N_EDGES + e];
        const int pos = off[d] + atomicAdd(&cursor[d], 1);
        csr_src[pos] = s;
        const float4* src4 = (const float4*)(edge_attr + (size_t)e * 32);
        ushort4* dst4 = (ushort4*)(ea_csr + (size_t)pos * 32);
#pragma unroll
        for (int i = 0; i < 8; i++) {
            const float4 v = src4[i];
            ushort4 u;
            u.x = f2bf(v.x); u.y = f2bf(v.y); u.z = f2bf(v.z); u.w = f2bf(v.w);
            dst4[i] = u;
        }
    }
}

// ---------------- K5: FUSED MFMA e-transform + aggregate + MLP+LN+GEMM -----
// 4 waves/block, wave = one node. Per 16-edge m-tile:
//   A-frag: one 16B coalesced load from ea_csr (lane: row=l&15, k-octet=l>>4)
//   16x MFMA 16x16x32 vs W_e B-frags (staged once per block in LDS, 16KB)
//   D -> per-wave he_s[16][260] bf16 (pad 4 -> conflict-free b16 writes)
//   aggregation: he row (b64) + xl gather + logit + exp + weighted sum.
// Epilogue zs/part are carved from the dead he_s pool (LDS total ~49.6KB).
__global__ __launch_bounds__(256) void k_fused(
    const int* __restrict__ off, const int* __restrict__ csr_src,
    const unsigned short* __restrict__ ea_csr,
    const float* __restrict__ W_e, const float* __restrict__ att,
    const unsigned short* __restrict__ xl_bf, const unsigned short* __restrict__ xr_bf,
    const float* __restrict__ x, const float* __restrict__ bias_gat,
    const float* __restrict__ W1, const float* __restrict__ b1,
    const float* __restrict__ gamma, const float* __restrict__ beta,
    const float* __restrict__ W2, const float* __restrict__ b2,
    float* __restrict__ out)
{
    __shared__ unsigned short bfrag_s[16][64][8];   // 16 KB: W_e bf16 B-frags
    __shared__ char pool[4][8320];                  // per-wave he_s[16][260]; reused as zs/part
    __shared__ float xs[4][64];
    __shared__ float redS[4][4], redQ[4][4];

    const int n0 = blockIdx.x * 4;
    const int t = threadIdx.x;
    const int lane = t & 63, wv = t >> 6;
    const int node = n0 + wv;

    for (int i = t; i < 4 * 64; i += 256) xs[i >> 6][i & 63] = x[n0 * 64 + i];

    // stage all 16 B-frags: slot = nt*64 + ls; lane ls: col = nt*16+(ls&15), k = (ls>>4)*8+j
    for (int i = t; i < 16 * 64; i += 256) {
        const int nt = i >> 6, ls = i & 63;
        const int col = nt * 16 + (ls & 15);
        const int kb = (ls >> 4) * 8;
        unsigned short tmp[8];
#pragma unroll
        for (int j = 0; j < 8; j++) tmp[j] = f2bf(W_e[(kb + j) * 256 + col]);
        *(ushort4*)&bfrag_s[nt][ls][0] = make_ushort4(tmp[0], tmp[1], tmp[2], tmp[3]);
        *(ushort4*)&bfrag_s[nt][ls][4] = make_ushort4(tmp[4], tmp[5], tmp[6], tmp[7]);
    }
    __syncthreads();

    unsigned short (*he)[260] = (unsigned short (*)[260])pool[wv];

    const float4 att4 = ((const float4*)att)[lane];
    const ushort4 xru = ((const ushort4*)(xr_bf + (size_t)node * 256))[lane];
    const float xr0 = bf2f(xru.x), xr1 = bf2f(xru.y), xr2 = bf2f(xru.z), xr3 = bf2f(xru.w);

    const int mylo = off[node], myhi = off[node + 1];
    const int arow = lane & 15, koct = lane >> 4;
    float4 g = make_float4(0.f, 0.f, 0.f, 0.f);
    float dsum = 0.f;

    for (int p0 = mylo; p0 < myhi; p0 += 16) {
        // A-frag (clamped pads duplicate the last edge; masked at exp)
        const int pa = min(p0 + arow, myhi - 1);
        const bf16x8 af = *(const bf16x8*)(ea_csr + (size_t)pa * 32 + koct * 8);
        // he = ea @ W_e via 16 MFMAs; D: row=(l>>4)*4+r (edge), col=nt*16+(l&15)
#pragma unroll 4
        for (int nt = 0; nt < 16; nt++) {
            const bf16x8 bfr = *(const bf16x8*)&bfrag_s[nt][lane][0];
            f32x4 dacc = {0.f, 0.f, 0.f, 0.f};
            dacc = __builtin_amdgcn_mfma_f32_16x16x32_bf16(af, bfr, dacc, 0, 0, 0);
#pragma unroll
            for (int r = 0; r < 4; r++)
                he[koct * 4 + r][nt * 16 + arow] = f2bf(dacc[r]);
        }
        // aggregation: 2 sub-groups of 8 edges
#pragma unroll
        for (int jb = 0; jb < 16; jb += 8) {
            ushort4 xlr[8];
#pragma unroll
            for (int jj = 0; jj < 8; jj++) {
                const int p = min(p0 + jb + jj, myhi - 1);
                const int src = csr_src[p];
                xlr[jj] = ((const ushort4*)(xl_bf + (size_t)src * 256))[lane];
            }
#pragma unroll
            for (int jj = 0; jj < 8; jj++) {
                const ushort4 h4 = *(const ushort4*)&he[jb + jj][lane * 4];
                float4 rf;
                rf.x = bf2f(xlr[jj].x); rf.y = bf2f(xlr[jj].y);
                rf.z = bf2f(xlr[jj].z); rf.w = bf2f(xlr[jj].w);
                float4 m;
                m.x = bf2f(h4.x) + rf.x + xr0;
                m.y = bf2f(h4.y) + rf.y + xr1;
                m.z = bf2f(h4.z) + rf.z + xr2;
                m.w = bf2f(h4.w) + rf.w + xr3;
                m.x = (m.x > 0.f) ? m.x : NEG_SLOPE * m.x;
                m.y = (m.y > 0.f) ? m.y : NEG_SLOPE * m.y;
                m.z = (m.z > 0.f) ? m.z : NEG_SLOPE * m.z;
                m.w = (m.w > 0.f) ? m.w : NEG_SLOPE * m.w;
                float s = m.x * att4.x + m.y * att4.y + m.z * att4.z + m.w * att4.w;
                s += __shfl_xor(s, 1, 64);
                s += __shfl_xor(s, 2, 64);
                s += __shfl_xor(s, 4, 64);
                s += __shfl_xor(s, 8, 64);   // 16-lane group = one head
                float wexp = __expf(fminf(s, 60.f));
                if (p0 + jb + jj >= myhi) wexp = 0.f;   // mask pad slots
                dsum += wexp;
                g.x = fmaf(wexp, rf.x, g.x);
                g.y = fmaf(wexp, rf.y, g.y);
                g.z = fmaf(wexp, rf.z, g.z);
                g.w = fmaf(wexp, rf.w, g.w);
            }
        }
    }
    // normalize; park in zs (carved from own wave's dead he_s region)
    const float inv = 1.f / (dsum + 1e-16f);
    g.x *= inv; g.y *= inv; g.z *= inv; g.w *= inv;
    ((float4*)pool[wv])[lane] = g;
    __syncthreads();

    // xl1 = tanh(x@W1+b1), channel t, 4 nodes
    float a1[4];
    const float b1v = b1[t];
#pragma unroll
    for (int n = 0; n < 4; n++) a1[n] = b1v;
    for (int k = 0; k < 64; k++) {
        const float w1v = W1[k * 256 + t];
#pragma unroll
        for (int n = 0; n < 4; n++) a1[n] = fmaf(xs[n][k], w1v, a1[n]);
    }

    const float bg = bias_gat[t];
    float z[4];
#pragma unroll
    for (int n = 0; n < 4; n++) z[n] = tanhf(a1[n]) + ((const float*)pool[n])[t] + bg;

    // LayerNorm over 256 channels per node
    const float gm = gamma[t], bt = beta[t];
#pragma unroll
    for (int n = 0; n < 4; n++) {
        float s = z[n], q = z[n] * z[n];
#pragma unroll
        for (int m = 1; m < 64; m <<= 1) { s += __shfl_xor(s, m, 64); q += __shfl_xor(q, m, 64); }
        if (lane == 0) { redS[n][wv] = s; redQ[n][wv] = q; }
    }
    __syncthreads();
#pragma unroll
    for (int n = 0; n < 4; n++) {
        const float s = redS[n][0] + redS[n][1] + redS[n][2] + redS[n][3];
        const float q = redQ[n][0] + redQ[n][1] + redQ[n][2] + redQ[n][3];
        const float mu = s * (1.f / 256.f);
        const float var = q * (1.f / 256.f) - mu * mu;
        const float ivn = rsqrtf(var + LN_EPS);
        ((float*)pool[n])[t] = (z[n] - mu) * ivn * gm + bt;
    }
    __syncthreads();

    // out = tanh(z@W2 + b2): thread t -> output col j=t&63, K-chunk q=t>>6
    // partials at pool[q]+4096 (disjoint from zs region [0,1024))
    const int j = t & 63, q = t >> 6;
    float p[4] = {0.f, 0.f, 0.f, 0.f};
    for (int c0 = 0; c0 < 64; c0++) {
        const int c = q * 64 + c0;
        const float w2v = W2[c * 64 + j];
#pragma unroll
        for (int n = 0; n < 4; n++) p[n] = fmaf(((const float*)pool[n])[c], w2v, p[n]);
    }
#pragma unroll
    for (int n = 0; n < 4; n++) ((float*)(pool[q] + 4096))[n * 64 + j] = p[n];
    __syncthreads();
    {
        const int n = t >> 6, jj = t & 63;
        float s = b2[jj];
#pragma unroll
        for (int u = 0; u < 4; u++) s += ((const float*)(pool[u] + 4096))[n * 64 + jj];
        out[(n0 + n) * 64 + jj] = tanhf(s);
    }
}

// ---------------- launcher --------------------------------------------------
extern "C" void kernel_launch(void* const* d_in, const int* in_sizes, int n_in,
                              void* d_out, int out_size, void* d_ws, size_t ws_size,
                              hipStream_t stream)
{
    const float* x         = (const float*)d_in[0];
    const int*   ei        = (const int*)d_in[1];
    const float* edge_attr = (const float*)d_in[2];
    const float* W_l       = (const float*)d_in[3];
    const float* b_l       = (const float*)d_in[4];
    const float* W_r       = (const float*)d_in[5];
    const float* b_r       = (const float*)d_in[6];
    const float* W_e       = (const float*)d_in[7];
    const float* att       = (const float*)d_in[8];
    const float* bias_gat  = (const float*)d_in[9];
    const float* W1        = (const float*)d_in[10];
    const float* b1        = (const float*)d_in[11];
    const float* gamma     = (const float*)d_in[12];
    const float* beta      = (const float*)d_in[13];
    const float* W2        = (const float*)d_in[14];
    const float* b2        = (const float*)d_in[15];
    float* out = (float*)d_out;

    char* ws = (char*)d_ws;
    unsigned short* xl_bf  = (unsigned short*)ws;  ws += (size_t)N_NODES * HC * 2;   // 25.6 MB
    unsigned short* xr_bf  = (unsigned short*)ws;  ws += (size_t)N_NODES * HC * 2;   // 25.6 MB
    unsigned short* ea_csr = (unsigned short*)ws;  ws += (size_t)N_EDGES * 32 * 2;   // 51.2 MB
    int* csr_src           = (int*)ws;             ws += (size_t)N_EDGES * 4;
    int* count             = (int*)ws;             ws += (size_t)N_NODES * 4;
    int* cursor            = (int*)ws;             ws += (size_t)N_NODES * 4;
    int* off               = (int*)ws;             ws += (size_t)(N_NODES + 1) * 4;

    // zero count + cursor (contiguous)
    hipMemsetAsync(count, 0, 2 * (size_t)N_NODES * sizeof(int), stream);

    k_node_transform<<<N_NODES / 8, 256, 0, stream>>>(x, W_l, b_l, W_r, b_r, xl_bf, xr_bf);
    k_hist<<<(N_EDGES + 255) / 256, 256, 0, stream>>>(ei, count);
    k_scan<<<1, 1024, 0, stream>>>(count, off);
    k_scatter<<<(N_EDGES + 255) / 256, 256, 0, stream>>>(ei, off, cursor, edge_attr,
                                                         csr_src, ea_csr);
    k_fused<<<N_NODES / 4, 256, 0, stream>>>(off, csr_src, ea_csr, W_e, att,
                                             xl_bf, xr_bf, x, bias_gat,
                                             W1, b1, gamma, beta, W2, b2, out);
}

// Round 11
// 755.685 us; speedup vs baseline: 1.5773x; 1.2518x over previous
//
#include <hip/hip_runtime.h>
#include <math.h>

#define N_NODES 50000
#define N_EDGES 800000
#define HID 64
#define HEADS 4
#define HC 256
#define NEG_SLOPE 0.2f
#define LN_EPS 1e-5f

typedef __attribute__((ext_vector_type(8))) short bf16x8;
typedef __attribute__((ext_vector_type(8))) unsigned short u16x8;
typedef __attribute__((ext_vector_type(4))) float f32x4;

__device__ __forceinline__ float bf2f(unsigned short u) {
    return __uint_as_float(((unsigned int)u) << 16);
}
__device__ __forceinline__ unsigned short f2bf(float f) {
    unsigned int u = __float_as_uint(f);
    u = (u + 0x7fffu + ((u >> 16) & 1u)) >> 16;   // RNE
    return (unsigned short)u;
}

// ---------------- K1: node transform -> TRANSPOSED-TILED bf16 xl_t / xr_t --
// xl_t[node][pos], pos = (c&15)*16 + (c>>4) for channel c. Lane(arow) then
// reads channels {nt*16+arow : nt=0..15} as 16 contiguous ushorts.
__global__ __launch_bounds__(256) void k_node_transform(
    const float* __restrict__ x,
    const float* __restrict__ W_l, const float* __restrict__ b_l,
    const float* __restrict__ W_r, const float* __restrict__ b_r,
    unsigned short* __restrict__ xl_t, unsigned short* __restrict__ xr_t)
{
    __shared__ float xs[8][64];
    __shared__ unsigned short tl[8][256], tr[8][256];
    const int n0 = blockIdx.x * 8;
    const int t = threadIdx.x;
    for (int i = t; i < 8 * 64; i += 256) xs[i >> 6][i & 63] = x[n0 * 64 + i];
    __syncthreads();

    float accl[8], accr[8];
    const float bl = b_l[t], br = b_r[t];
#pragma unroll
    for (int n = 0; n < 8; n++) { accl[n] = bl; accr[n] = br; }
    for (int k = 0; k < 64; k++) {
        const float wl = W_l[k * 256 + t];
        const float wr = W_r[k * 256 + t];
#pragma unroll
        for (int n = 0; n < 8; n++) {
            accl[n] = fmaf(xs[n][k], wl, accl[n]);
            accr[n] = fmaf(xs[n][k], wr, accr[n]);
        }
    }
    const int pos = (t & 15) * 16 + (t >> 4);   // transposed-tiled position of channel t
#pragma unroll
    for (int n = 0; n < 8; n++) {
        tl[n][pos] = f2bf(accl[n]);
        tr[n][pos] = f2bf(accr[n]);
    }
    __syncthreads();
    // coalesced write-out: thread t -> node t>>5, 8 ushorts at (t&31)*8
    const int n = t >> 5, q = t & 31;
    ushort4 v0 = *(const ushort4*)&tl[n][q * 8];
    ushort4 v1 = *(const ushort4*)&tl[n][q * 8 + 4];
    ushort4 w0 = *(const ushort4*)&tr[n][q * 8];
    ushort4 w1 = *(const ushort4*)&tr[n][q * 8 + 4];
    *(ushort4*)(xl_t + (size_t)(n0 + n) * 256 + q * 8)     = v0;
    *(ushort4*)(xl_t + (size_t)(n0 + n) * 256 + q * 8 + 4) = v1;
    *(ushort4*)(xr_t + (size_t)(n0 + n) * 256 + q * 8)     = w0;
    *(ushort4*)(xr_t + (size_t)(n0 + n) * 256 + q * 8 + 4) = w1;
}

// ---------------- K1b: prep W_e B-frags (bf16) + att_t ----------------------
__global__ __launch_bounds__(256) void k_prep(
    const float* __restrict__ W_e, const float* __restrict__ att,
    unsigned short* __restrict__ wfrag, unsigned short* __restrict__ att_t)
{
    const int t = threadIdx.x;
#pragma unroll
    for (int s = 0; s < 4; s++) {
        const int slot = t * 4 + s;            // 1024 slots = 16 nt x 64 lanes
        const int nt = slot >> 6, ls = slot & 63;
        const int col = nt * 16 + (ls & 15);
        const int kb = (ls >> 4) * 8;
#pragma unroll
        for (int j = 0; j < 8; j++)
            wfrag[slot * 8 + j] = f2bf(W_e[(kb + j) * 256 + col]);
    }
    // att_t[pos] = att_flat[c], pos = (c&15)*16+(c>>4)  (16x16 transpose)
    att_t[t] = f2bf(att[(t & 15) * 16 + (t >> 4)]);
}

// ---------------- K2: histogram of dst ------------------------------------
__global__ __launch_bounds__(256) void k_hist(const int* __restrict__ ei, int* __restrict__ count)
{
    const int e = blockIdx.x * 256 + threadIdx.x;
    if (e < N_EDGES) atomicAdd(&count[ei[N_EDGES + e]], 1);
}

// ---------------- K3: exclusive scan (single block) ------------------------
__global__ __launch_bounds__(1024) void k_scan(const int* __restrict__ count, int* __restrict__ off)
{
    __shared__ int wsum[16];
    __shared__ int s_carry;
    const int t = threadIdx.x, lane = t & 63, wv = t >> 6;
    if (t == 0) s_carry = 0;
    __syncthreads();
    for (int base = 0; base < N_NODES; base += 8192) {
        const int idx0 = base + t * 8;
        int v[8];
#pragma unroll
        for (int j = 0; j < 8; j++) { int i = idx0 + j; v[j] = (i < N_NODES) ? count[i] : 0; }
#pragma unroll
        for (int j = 1; j < 8; j++) v[j] += v[j - 1];
        const int tot = v[7];
        int sc = tot;
#pragma unroll
        for (int s = 1; s < 64; s <<= 1) { int o = __shfl_up(sc, s, 64); if (lane >= s) sc += o; }
        if (lane == 63) wsum[wv] = sc;
        __syncthreads();
        const int carry = s_carry;
        int woff = 0;
        for (int u = 0; u < wv; u++) woff += wsum[u];
        const int ebase = carry + woff + (sc - tot);
#pragma unroll
        for (int j = 0; j < 8; j++) {
            int i = idx0 + j;
            if (i < N_NODES) off[i] = ebase + (j ? v[j - 1] : 0);
        }
        __syncthreads();
        if (t == 0) { int tt = 0; for (int u = 0; u < 16; u++) tt += wsum[u]; s_carry = carry + tt; }
        __syncthreads();
    }
    if (threadIdx.x == 0) off[N_NODES] = s_carry;
}

// ---------------- K4: scatter src + PERMUTED bf16 edge_attr into CSR -------
__global__ __launch_bounds__(256) void k_scatter(
    const int* __restrict__ ei, const int* __restrict__ off, int* __restrict__ cursor,
    const float* __restrict__ edge_attr,
    int* __restrict__ csr_src, unsigned short* __restrict__ ea_csr)
{
    const int e = blockIdx.x * 256 + threadIdx.x;
    if (e < N_EDGES) {
        const int s = ei[e];
        const int d = ei[N_EDGES + e];
        const int pos = off[d] + atomicAdd(&cursor[d], 1);
        csr_src[pos] = s;
        const float4* src4 = (const float4*)(edge_attr + (size_t)e * 32);
        ushort4* dst4 = (ushort4*)(ea_csr + (size_t)pos * 32);
#pragma unroll
        for (int i = 0; i < 8; i++) {
            const float4 v = src4[i];
            ushort4 u;
            u.x = f2bf(v.x); u.y = f2bf(v.y); u.z = f2bf(v.z); u.w = f2bf(v.w);
            dst4[i] = u;
        }
    }
}

// ---------------- K5: FUSED all-register D-layout edge pipeline ------------
// 4 waves/block, wave = one node. Lane (arow=l&15, koct=l>>4) owns, for its
// 4 edges (D rows koct*4+r), channels {nt*16+arow}. No he LDS round-trip:
// logit and aggregation consume the MFMA D fragments in registers.
__global__ __launch_bounds__(256) void k_fused(
    const int* __restrict__ off, const int* __restrict__ csr_src,
    const unsigned short* __restrict__ ea_csr,
    const unsigned short* __restrict__ wfrag, const unsigned short* __restrict__ att_t,
    const unsigned short* __restrict__ xl_t, const unsigned short* __restrict__ xr_t,
    const float* __restrict__ x, const float* __restrict__ bias_gat,
    const float* __restrict__ W1, const float* __restrict__ b1,
    const float* __restrict__ gamma, const float* __restrict__ beta,
    const float* __restrict__ W2, const float* __restrict__ b2,
    float* __restrict__ out)
{
    __shared__ unsigned short bfrag_s[16][64][8];   // 16 KB W_e B-frags
    __shared__ float zs[4][256];
    __shared__ float xs[4][64];
    __shared__ float part[4][4][64];
    __shared__ float redS[4][4], redQ[4][4];

    const int n0 = blockIdx.x * 4;
    const int t = threadIdx.x;
    const int lane = t & 63, wv = t >> 6;
    const int node = n0 + wv;
    const int arow = lane & 15, koct = lane >> 4;

    for (int i = t; i < 4 * 64; i += 256) xs[i >> 6][i & 63] = x[n0 * 64 + i];
    // stage B-frags (bf16 copy, coalesced)
    for (int i = t; i < 1024; i += 256)
        *(u16x8*)&bfrag_s[i >> 6][i & 63][0] = *(const u16x8*)(wfrag + i * 8);
    __syncthreads();

    const u16x8 attL = *(const u16x8*)(att_t + arow * 16);
    const u16x8 attH = *(const u16x8*)(att_t + arow * 16 + 8);
    const u16x8 xrL  = *(const u16x8*)(xr_t + (size_t)node * 256 + arow * 16);
    const u16x8 xrH  = *(const u16x8*)(xr_t + (size_t)node * 256 + arow * 16 + 8);

    const int mylo = off[node], myhi = off[node + 1];
    float g[16];
#pragma unroll
    for (int i = 0; i < 16; i++) g[i] = 0.f;
    float dsum[4] = {0.f, 0.f, 0.f, 0.f};

    for (int p0 = mylo; p0 < myhi; p0 += 16) {
        // srcs: lane L holds csr_src at position p0+(L&15)
        const int sv = csr_src[min(p0 + arow, myhi - 1)];
        const int pa = min(p0 + arow, myhi - 1);
        const bf16x8 af = *(const bf16x8*)(ea_csr + (size_t)pa * 32 + koct * 8);
        int src[4];
#pragma unroll
        for (int r = 0; r < 4; r++) src[r] = __shfl(sv, koct * 4 + r, 64);
        u16x8 xlo[4], xhi[4];
#pragma unroll
        for (int r = 0; r < 4; r++) {
            const unsigned short* bp = xl_t + (size_t)src[r] * 256 + arow * 16;
            xlo[r] = *(const u16x8*)bp;
            xhi[r] = *(const u16x8*)(bp + 8);
        }
        float s_[4][4];
#pragma unroll
        for (int r = 0; r < 4; r++)
#pragma unroll
            for (int h = 0; h < 4; h++) s_[r][h] = 0.f;

#pragma unroll
        for (int nt = 0; nt < 16; nt++) {
            const bf16x8 bfr = *(const bf16x8*)&bfrag_s[nt][lane][0];
            f32x4 dacc = {0.f, 0.f, 0.f, 0.f};
            dacc = __builtin_amdgcn_mfma_f32_16x16x32_bf16(af, bfr, dacc, 0, 0, 0);
            const float xrv = bf2f(nt < 8 ? (unsigned short)xrL[nt & 7] : (unsigned short)xrH[nt & 7]);
            const float atv = bf2f(nt < 8 ? (unsigned short)attL[nt & 7] : (unsigned short)attH[nt & 7]);
            const int h = nt >> 2;
#pragma unroll
            for (int r = 0; r < 4; r++) {
                const float xv = bf2f(nt < 8 ? (unsigned short)xlo[r][nt & 7] : (unsigned short)xhi[r][nt & 7]);
                float mm = dacc[r] + xv + xrv;
                mm = (mm > 0.f) ? mm : NEG_SLOPE * mm;
                s_[r][h] = fmaf(atv, mm, s_[r][h]);
            }
        }
        // reduce logits over the 16 arow lanes of this koct group
#pragma unroll
        for (int r = 0; r < 4; r++)
#pragma unroll
            for (int h = 0; h < 4; h++) {
                float v = s_[r][h];
                v += __shfl_xor(v, 1, 64);
                v += __shfl_xor(v, 2, 64);
                v += __shfl_xor(v, 4, 64);
                v += __shfl_xor(v, 8, 64);
                s_[r][h] = v;
            }
        // per-head: exp, dsum, aggregate (keeps w live-range at 4 regs)
#pragma unroll
        for (int h = 0; h < 4; h++) {
            float w4[4];
#pragma unroll
            for (int r = 0; r < 4; r++) {
                const bool ok = (p0 + koct * 4 + r) < myhi;
                w4[r] = ok ? __expf(fminf(s_[r][h], 60.f)) : 0.f;
            }
            dsum[h] += w4[0] + w4[1] + w4[2] + w4[3];
#pragma unroll
            for (int q = 0; q < 4; q++) {
                const int nt = h * 4 + q;
                float acc = g[nt];
#pragma unroll
                for (int r = 0; r < 4; r++) {
                    const float xv = bf2f(nt < 8 ? (unsigned short)xlo[r][nt & 7] : (unsigned short)xhi[r][nt & 7]);
                    acc = fmaf(w4[r], xv, acc);
                }
                g[nt] = acc;
            }
        }
    }
    // cross-koct reduction (4 partial groups -> full sums)
#pragma unroll
    for (int i = 0; i < 16; i++) {
        float v = g[i];
        v += __shfl_xor(v, 16, 64);
        v += __shfl_xor(v, 32, 64);
        g[i] = v;
    }
#pragma unroll
    for (int h = 0; h < 4; h++) {
        float v = dsum[h];
        v += __shfl_xor(v, 16, 64);
        v += __shfl_xor(v, 32, 64);
        dsum[h] = v;
    }
    float inv[4];
#pragma unroll
    for (int h = 0; h < 4; h++) inv[h] = 1.f / (dsum[h] + 1e-16f);
#pragma unroll
    for (int nt = 0; nt < 16; nt++) g[nt] *= inv[nt >> 2];
    if (koct == 0) {
#pragma unroll
        for (int nt = 0; nt < 16; nt++) zs[wv][nt * 16 + arow] = g[nt];
    }
    __syncthreads();

    // xl1 = tanh(x@W1+b1), channel t, 4 nodes
    float a1[4];
    const float b1v = b1[t];
#pragma unroll
    for (int n = 0; n < 4; n++) a1[n] = b1v;
    for (int k = 0; k < 64; k++) {
        const float w1v = W1[k * 256 + t];
#pragma unroll
        for (int n = 0; n < 4; n++) a1[n] = fmaf(xs[n][k], w1v, a1[n]);
    }

    const float bg = bias_gat[t];
    float z[4];
#pragma unroll
    for (int n = 0; n < 4; n++) z[n] = tanhf(a1[n]) + zs[n][t] + bg;

    // LayerNorm over 256 channels per node
    const float gm = gamma[t], bt = beta[t];
#pragma unroll
    for (int n = 0; n < 4; n++) {
        float s = z[n], q = z[n] * z[n];
#pragma unroll
        for (int m = 1; m < 64; m <<= 1) { s += __shfl_xor(s, m, 64); q += __shfl_xor(q, m, 64); }
        if (lane == 0) { redS[n][wv] = s; redQ[n][wv] = q; }
    }
    __syncthreads();
#pragma unroll
    for (int n = 0; n < 4; n++) {
        const float s = redS[n][0] + redS[n][1] + redS[n][2] + redS[n][3];
        const float q = redQ[n][0] + redQ[n][1] + redQ[n][2] + redQ[n][3];
        const float mu = s * (1.f / 256.f);
        const float var = q * (1.f / 256.f) - mu * mu;
        const float ivn = rsqrtf(var + LN_EPS);
        zs[n][t] = (z[n] - mu) * ivn * gm + bt;
    }
    __syncthreads();

    // out = tanh(z@W2 + b2): thread t -> output col j=t&63, K-chunk q=t>>6
    const int j = t & 63, q = t >> 6;
    float p[4] = {0.f, 0.f, 0.f, 0.f};
    for (int c0 = 0; c0 < 64; c0++) {
        const int c = q * 64 + c0;
        const float w2v = W2[c * 64 + j];
#pragma unroll
        for (int n = 0; n < 4; n++) p[n] = fmaf(zs[n][c], w2v, p[n]);
    }
#pragma unroll
    for (int n = 0; n < 4; n++) part[n][q][j] = p[n];
    __syncthreads();
    {
        const int n = t >> 6, jj = t & 63;
        const float s = part[n][0][jj] + part[n][1][jj] + part[n][2][jj] + part[n][3][jj];
        out[(n0 + n) * 64 + jj] = tanhf(s + b2[jj]);
    }
}

// ---------------- launcher --------------------------------------------------
extern "C" void kernel_launch(void* const* d_in, const int* in_sizes, int n_in,
                              void* d_out, int out_size, void* d_ws, size_t ws_size,
                              hipStream_t stream)
{
    const float* x         = (const float*)d_in[0];
    const int*   ei        = (const int*)d_in[1];
    const float* edge_attr = (const float*)d_in[2];
    const float* W_l       = (const float*)d_in[3];
    const float* b_l       = (const float*)d_in[4];
    const float* W_r       = (const float*)d_in[5];
    const float* b_r       = (const float*)d_in[6];
    const float* W_e       = (const float*)d_in[7];
    const float* att       = (const float*)d_in[8];
    const float* bias_gat  = (const float*)d_in[9];
    const float* W1        = (const float*)d_in[10];
    const float* b1        = (const float*)d_in[11];
    const float* gamma     = (const float*)d_in[12];
    const float* beta      = (const float*)d_in[13];
    const float* W2        = (const float*)d_in[14];
    const float* b2        = (const float*)d_in[15];
    float* out = (float*)d_out;

    char* ws = (char*)d_ws;
    unsigned short* xl_t   = (unsigned short*)ws;  ws += (size_t)N_NODES * HC * 2;   // 25.6 MB
    unsigned short* xr_t   = (unsigned short*)ws;  ws += (size_t)N_NODES * HC * 2;   // 25.6 MB
    unsigned short* ea_csr = (unsigned short*)ws;  ws += (size_t)N_EDGES * 32 * 2;   // 51.2 MB
    int* csr_src           = (int*)ws;             ws += (size_t)N_EDGES * 4;
    int* count             = (int*)ws;             ws += (size_t)N_NODES * 4;
    int* cursor            = (int*)ws;             ws += (size_t)N_NODES * 4;
    int* off               = (int*)ws;             ws += (size_t)(N_NODES + 1) * 4;
    unsigned short* wfrag  = (unsigned short*)ws;  ws += 16 * 64 * 8 * 2;            // 16 KB
    unsigned short* att_t  = (unsigned short*)ws;  ws += 256 * 2;

    // zero count + cursor (contiguous)
    hipMemsetAsync(count, 0, 2 * (size_t)N_NODES * sizeof(int), stream);

    k_node_transform<<<N_NODES / 8, 256, 0, stream>>>(x, W_l, b_l, W_r, b_r, xl_t, xr_t);
    k_prep<<<1, 256, 0, stream>>>(W_e, att, wfrag, att_t);
    k_hist<<<(N_EDGES + 255) / 256, 256, 0, stream>>>(ei, count);
    k_scan<<<1, 1024, 0, stream>>>(count, off);
    k_scatter<<<(N_EDGES + 255) / 256, 256, 0, stream>>>(ei, off, cursor, edge_attr,
                                                         csr_src, ea_csr);
    k_fused<<<N_NODES / 4, 256, 0, stream>>>(off, csr_src, ea_csr, wfrag, att_t,
                                             xl_t, xr_t, x, bias_gat,
                                             W1, b1, gamma, beta, W2, b2, out);
}